// Round 2
// 490.908 us; speedup vs baseline: 1.0211x; 1.0211x over previous
//
#include <hip/hip_runtime.h>
#include <math.h>

// Problem constants (from reference)
#define BATCH 64
#define TDIM 512
#define FEAT 2048
#define HID 1024
#define KDIM 512
#define MROWS (BATCH * TDIM)  // 32768 flat feats rows
#define TCH 16                // k4 time-chunks
#define TCLEN (TDIM / TCH)    // 32 t per chunk

#define U4 (KDIM * FEAT / 4)  // 262,144 float4 units of U

typedef __attribute__((ext_vector_type(8))) short short8;
typedef __attribute__((ext_vector_type(4))) float floatx4;

// global -> LDS direct DMA, 16B per lane; LDS dest is wave-uniform base,
// lane i lands at base + i*16 (per-lane LDS address is NOT honored).
#define GLL16(g, l)                                                     \
    __builtin_amdgcn_global_load_lds(                                   \
        (const __attribute__((address_space(1))) void*)(g),             \
        (__attribute__((address_space(3))) void*)(l), 16, 0, 0)

// ---------------------------------------------------------------------------
// f32 -> bf16 (round-to-nearest-even)
// ---------------------------------------------------------------------------
__device__ __forceinline__ unsigned short f2bf(float x) {
    unsigned int u = __float_as_uint(x);
    u += 0x7FFFu + ((u >> 16) & 1u);
    return (unsigned short)(u >> 16);
}

// ---------------------------------------------------------------------------
// k0n: blocks [0,256): convert U f32->bf16 (grid-stride)
//      blocks [256,8448): Whb[b,k] = hidden[b]·W[k] + bias[k]
//      (one wave per output, 4 waves/block)
// The 384 MB feats-conversion pass is GONE: k2n converts A on the fly.
// ---------------------------------------------------------------------------
__global__ __launch_bounds__(256) void k0n(const float* __restrict__ U,
                                           const float* __restrict__ hidden,
                                           const float* __restrict__ W,
                                           const float* __restrict__ bias,
                                           unsigned short* __restrict__ uB,
                                           float* __restrict__ whb) {
    int bx = blockIdx.x;
    if (bx < 256) {
        int stride = 256 * 256;
        for (int i = bx * 256 + threadIdx.x; i < U4; i += stride) {
            float4 v = ((const float4*)U)[i];
            ushort4 o;
            o.x = f2bf(v.x); o.y = f2bf(v.y); o.z = f2bf(v.z); o.w = f2bf(v.w);
            ((ushort4*)uB)[i] = o;
        }
    } else {
        int bid = bx - 256;                  // 0..8191
        int b = bid >> 7;                    // 0..63
        int k = (bid & 127) * 4 + (threadIdx.x >> 6);
        int lane = threadIdx.x & 63;
        const float* hrow = hidden + (size_t)b * HID;
        const float* wrow = W + (size_t)k * HID;
        float acc = 0.f;
        #pragma unroll 4
        for (int h = lane; h < HID; h += 64) acc += hrow[h] * wrow[h];
        #pragma unroll
        for (int off = 32; off > 0; off >>= 1) acc += __shfl_down(acc, off, 64);
        if (lane == 0) whb[b * KDIM + k] = acc + bias[k];
    }
}

// ---------------------------------------------------------------------------
// k2n: bf16 MFMA GEMM, full-N strip per block + fused tanh/dot(w) epilogue.
// Tile M=128 x N=512 (ALL of K-dim), BK=64, 512 thr = 8 waves (2m x 4n),
// wave-tile 64x128 (4x8 16x16x32 MFMAs per kk, kk in {0,1}).
// A (feats) is read as f32 ONCE (reg-staged: global f32 -> cvt bf16 ->
// swizzled ds_write_b128); A-regs for step t+1 prefetched during compute(t).
// B (uB bf16) staged via GLL16. Each block emits COMPLETE energies for its
// 128 rows (no k-partials, no 4x re-read of A).
// XOR swizzle (proven layout): LDS 16B-slot s holds chunk (row=s>>3,
// q=(s&7)^(row&7)); read chunk (row, kk*4+quad) at q'=(kk*4+quad)^(col&7).
// LDS 82 KB -> 1 block/CU; grid = 256 = #CUs.
// ---------------------------------------------------------------------------
__global__ __launch_bounds__(512, 2) void k2n(const float* __restrict__ feats,
                                              const unsigned short* __restrict__ uB,
                                              const float* __restrict__ whb,
                                              const float* __restrict__ wvec,
                                              float* __restrict__ energies) {
    __shared__ __align__(16) unsigned short As[128 * 64];  // 16 KB
    __shared__ __align__(16) unsigned short Bs[512 * 64];  // 64 KB
    __shared__ float sums[4][128];                         // 2 KB

    const int tid  = threadIdx.x;
    const int wave = tid >> 6;
    const int lane = tid & 63;
    const int row0 = blockIdx.x * 128;
    const int wm = wave >> 2;            // 0..1 (M)
    const int wn = wave & 3;             // 0..3 (N)
    const int col = lane & 15, quad = lane >> 4;

    // ---- A staging map: thread owns slots {tid, tid+512} of 1024 16B slots
    const int sr = tid >> 3;                  // row of slot tid (0..63)
    const int sc = (tid & 7) ^ (sr & 7);      // swizzled chunk
    const float* gA = feats + (size_t)(row0 + sr) * FEAT + sc * 8;
    unsigned short* lA0 = As + tid * 8;             // slot tid
    unsigned short* lA1 = As + (tid + 512) * 8;     // slot tid+512 (row sr+64, same chunk)

    // ---- B staging map: 4096 slots, 8 GLL16/thread
    const int bq = (lane & 7) ^ ((lane >> 3) & 7);
    const int br = wave * 8 + (lane >> 3);    // row within each 64-row g-group
    const unsigned short* gBp[8];
    unsigned short* lB[8];
    #pragma unroll
    for (int g = 0; g < 8; ++g) {
        gBp[g] = uB + (size_t)(g * 64 + br) * FEAT + bq * 8;
        lB[g]  = Bs + (g * 512 + wave * 64) * 8;   // wave-uniform base
    }

    floatx4 acc[4][8];
    #pragma unroll
    for (int i = 0; i < 4; ++i)
        #pragma unroll
        for (int j = 0; j < 8; ++j) acc[i][j] = (floatx4){0.f, 0.f, 0.f, 0.f};

    // prologue: A(0) into regs
    float4 a0 = *(const float4*)(gA);
    float4 a1 = *(const float4*)(gA + 4);
    float4 a2 = *(const float4*)(gA + (size_t)64 * FEAT);
    float4 a3 = *(const float4*)(gA + (size_t)64 * FEAT + 4);
    gA += 64;

    for (int f0 = 0; f0 < FEAT; f0 += 64) {
        // issue B DMA first (it's the drain-limiter at the barrier)
        #pragma unroll
        for (int g = 0; g < 8; ++g) { GLL16(gBp[g], lB[g]); gBp[g] += 64; }
        // convert + write A (regs loaded one iteration ago)
        short8 w0, w1;
        w0[0] = f2bf(a0.x); w0[1] = f2bf(a0.y); w0[2] = f2bf(a0.z); w0[3] = f2bf(a0.w);
        w0[4] = f2bf(a1.x); w0[5] = f2bf(a1.y); w0[6] = f2bf(a1.z); w0[7] = f2bf(a1.w);
        w1[0] = f2bf(a2.x); w1[1] = f2bf(a2.y); w1[2] = f2bf(a2.z); w1[3] = f2bf(a2.w);
        w1[4] = f2bf(a3.x); w1[5] = f2bf(a3.y); w1[6] = f2bf(a3.z); w1[7] = f2bf(a3.w);
        *(short8*)lA0 = w0;
        *(short8*)lA1 = w1;
        __syncthreads();   // drains GLL16 + ds_writes: tile ready

        // prefetch A(t+1) f32 into regs — latency hides under the MFMAs below
        if (f0 + 64 < FEAT) {
            a0 = *(const float4*)(gA);
            a1 = *(const float4*)(gA + 4);
            a2 = *(const float4*)(gA + (size_t)64 * FEAT);
            a3 = *(const float4*)(gA + (size_t)64 * FEAT + 4);
            gA += 64;
        }

        #pragma unroll
        for (int kk = 0; kk < 2; ++kk) {
            const int sw = ((kk * 4 + quad) ^ (col & 7)) * 8;
            short8 af[4], bf[8];
            #pragma unroll
            for (int i = 0; i < 4; ++i)
                af[i] = *(const short8*)&As[(wm * 64 + i * 16 + col) * 64 + sw];
            #pragma unroll
            for (int j = 0; j < 8; ++j)
                bf[j] = *(const short8*)&Bs[(wn * 128 + j * 16 + col) * 64 + sw];
            #pragma unroll
            for (int i = 0; i < 4; ++i)
                #pragma unroll
                for (int j = 0; j < 8; ++j)
                    acc[i][j] = __builtin_amdgcn_mfma_f32_16x16x32_bf16(
                        af[i], bf[j], acc[i][j], 0, 0, 0);
        }
        __syncthreads();   // readers done before next overwrite
    }

    // Epilogue. C/D layout: col = lane&15 (n/k-dim), row = quad*4 + reg (m).
    const int b = row0 >> 9;   // 128-row block stays within one batch (T=512)
    float wk[8], hk[8];
    #pragma unroll
    for (int j = 0; j < 8; ++j) {
        int k = wn * 128 + j * 16 + col;
        wk[j] = wvec[k];
        hk[j] = whb[b * KDIM + k];
    }
    #pragma unroll
    for (int i = 0; i < 4; ++i) {
        #pragma unroll
        for (int r = 0; r < 4; ++r) {
            float s = 0.f;
            #pragma unroll
            for (int j = 0; j < 8; ++j)
                s += tanhf(acc[i][j][r] + hk[j]) * wk[j];
            #pragma unroll
            for (int off = 8; off > 0; off >>= 1)
                s += __shfl_down(s, off, 16);
            if (col == 0)
                sums[wn][wm * 64 + i * 16 + quad * 4 + r] = s;
        }
    }
    __syncthreads();
    if (tid < 128)
        energies[row0 + tid] =
            sums[0][tid] + sums[1][tid] + sums[2][tid] + sums[3][tid];
}

// ---------------------------------------------------------------------------
// k3n: softmax over T per batch (energies are complete — no partial sum)
// ---------------------------------------------------------------------------
__global__ __launch_bounds__(512) void k3n(const float* __restrict__ energies,
                                           float* __restrict__ wout) {
    int b = blockIdx.x;
    int t = threadIdx.x;
    float e = energies[b * TDIM + t];

    __shared__ float sm[512];
    sm[t] = e;
    __syncthreads();
    #pragma unroll
    for (int s = 256; s > 0; s >>= 1) {
        if (t < s) sm[t] = fmaxf(sm[t], sm[t + s]);
        __syncthreads();
    }
    float m = sm[0];
    __syncthreads();
    float ex = __expf(e - m);
    sm[t] = ex;
    __syncthreads();
    #pragma unroll
    for (int s = 256; s > 0; s >>= 1) {
        if (t < s) sm[t] += sm[t + s];
        __syncthreads();
    }
    float inv = 1.f / sm[0];
    wout[b * TDIM + t] = ex * inv;
}

// ---------------------------------------------------------------------------
// k4n: T-chunked weighted pooling straight from f32 feats (no bf16 copy
// exists anymore). grid (TCH=16, BATCH); block covers FEAT=2048
// (8 f32/thread via 2x float4), TCLEN=32 time steps.
// ---------------------------------------------------------------------------
__global__ __launch_bounds__(256) void k4n(const float* __restrict__ feats,
                                           const float* __restrict__ weights,
                                           float* __restrict__ partial4) {
    int b  = blockIdx.y;
    int t0 = blockIdx.x * TCLEN;
    int f8 = threadIdx.x * 8;
    __shared__ float wsm[TCLEN];
    if (threadIdx.x < TCLEN) wsm[threadIdx.x] = weights[b * TDIM + t0 + threadIdx.x];
    __syncthreads();

    const float* fp = feats + ((size_t)b * TDIM + t0) * FEAT + f8;
    float a[8];
    #pragma unroll
    for (int e = 0; e < 8; ++e) a[e] = 0.f;
    #pragma unroll 4
    for (int t = 0; t < TCLEN; ++t) {
        float4 v0 = *(const float4*)(fp + (size_t)t * FEAT);
        float4 v1 = *(const float4*)(fp + (size_t)t * FEAT + 4);
        float w = wsm[t];
        a[0] += v0.x * w; a[1] += v0.y * w; a[2] += v0.z * w; a[3] += v0.w * w;
        a[4] += v1.x * w; a[5] += v1.y * w; a[6] += v1.z * w; a[7] += v1.w * w;
    }
    float* op = partial4 + ((size_t)blockIdx.x * BATCH + b) * FEAT + f8;
    float4 o0 = {a[0], a[1], a[2], a[3]};
    float4 o1 = {a[4], a[5], a[6], a[7]};
    *(float4*)op = o0;
    *(float4*)(op + 4) = o1;
}

__global__ __launch_bounds__(256) void k5_reduce(const float* __restrict__ partial4,
                                                 float* __restrict__ out) {
    int i4 = blockIdx.x * 256 + threadIdx.x;  // float4 index into B*FEAT
    float4 s = ((const float4*)partial4)[i4];
    #pragma unroll
    for (int c = 1; c < TCH; ++c) {
        float4 v = ((const float4*)partial4)[(size_t)c * (BATCH * FEAT / 4) + i4];
        s.x += v.x; s.y += v.y; s.z += v.z; s.w += v.w;
    }
    ((float4*)out)[i4] = s;
}

// ---------------------------------------------------------------------------
// Fallback-path kernels (tiny ws): original k1 + f32 tile GEMM + direct pool
// ---------------------------------------------------------------------------
#define BM 128
#define BN 128
#define BF 16
#define LDSPAD 4

__global__ __launch_bounds__(256) void k1_whb(const float* __restrict__ hidden,
                                              const float* __restrict__ W,
                                              const float* __restrict__ bias,
                                              float* __restrict__ whb) {
    int b = blockIdx.y;
    int k = blockIdx.x * 4 + (threadIdx.x >> 6);
    int lane = threadIdx.x & 63;
    const float* hrow = hidden + (size_t)b * HID;
    const float* wrow = W + (size_t)k * HID;
    float acc = 0.f;
    #pragma unroll 4
    for (int h = lane; h < HID; h += 64) acc += hrow[h] * wrow[h];
    #pragma unroll
    for (int off = 32; off > 0; off >>= 1) acc += __shfl_down(acc, off, 64);
    if (lane == 0) whb[b * KDIM + k] = acc + bias[k];
}

__global__ __launch_bounds__(256) void k2_energy(const float* __restrict__ feats,
                                                 const float* __restrict__ U,
                                                 const float* __restrict__ whb,
                                                 const float* __restrict__ wvec,
                                                 float* __restrict__ partial) {
    __shared__ __align__(16) float As[BF][BM + LDSPAD];
    __shared__ __align__(16) float Us[BF][BN + LDSPAD];

    const int row0 = blockIdx.x * BM;
    const int k0   = blockIdx.y * BN;
    const int tid  = threadIdx.x;
    const int tx   = tid & 15;
    const int ty   = tid >> 4;

    float acc[8][8];
    #pragma unroll
    for (int i = 0; i < 8; ++i)
        #pragma unroll
        for (int j = 0; j < 8; ++j) acc[i][j] = 0.f;

    for (int f0 = 0; f0 < FEAT; f0 += BF) {
        #pragma unroll
        for (int l = 0; l < 2; ++l) {
            int li = tid + l * 256;
            int r  = li >> 2;
            int c4 = (li & 3) * 4;
            float4 av = *(const float4*)(feats + (size_t)(row0 + r) * FEAT + f0 + c4);
            float4 uv = *(const float4*)(U     + (size_t)(k0   + r) * FEAT + f0 + c4);
            As[c4 + 0][r] = av.x; As[c4 + 1][r] = av.y;
            As[c4 + 2][r] = av.z; As[c4 + 3][r] = av.w;
            Us[c4 + 0][r] = uv.x; Us[c4 + 1][r] = uv.y;
            Us[c4 + 2][r] = uv.z; Us[c4 + 3][r] = uv.w;
        }
        __syncthreads();
        #pragma unroll
        for (int kf = 0; kf < BF; ++kf) {
            float4 a0 = *(const float4*)&As[kf][ty * 8];
            float4 a1 = *(const float4*)&As[kf][ty * 8 + 4];
            float4 u0 = *(const float4*)&Us[kf][tx * 8];
            float4 u1 = *(const float4*)&Us[kf][tx * 8 + 4];
            float a[8] = {a0.x, a0.y, a0.z, a0.w, a1.x, a1.y, a1.z, a1.w};
            float u[8] = {u0.x, u0.y, u0.z, u0.w, u1.x, u1.y, u1.z, u1.w};
            #pragma unroll
            for (int i = 0; i < 8; ++i)
                #pragma unroll
                for (int j = 0; j < 8; ++j) acc[i][j] += a[i] * u[j];
        }
        __syncthreads();
    }

    const int b = row0 >> 9;
    float psum[8];
    #pragma unroll
    for (int i = 0; i < 8; ++i) {
        float s = 0.f;
        #pragma unroll
        for (int j = 0; j < 8; ++j) {
            int k = k0 + tx * 8 + j;
            s += tanhf(acc[i][j] + whb[b * KDIM + k]) * wvec[k];
        }
        psum[i] = s;
    }
    #pragma unroll
    for (int off = 8; off > 0; off >>= 1)
        #pragma unroll
        for (int i = 0; i < 8; ++i) psum[i] += __shfl_down(psum[i], off, 16);

    if (tx == 0) {
        int c = blockIdx.y;
        #pragma unroll
        for (int i = 0; i < 8; ++i)
            partial[c * MROWS + row0 + ty * 8 + i] = psum[i];
    }
}

__global__ __launch_bounds__(512) void k3_softmax(const float* __restrict__ partial,
                                                  float* __restrict__ wout) {
    int b = blockIdx.x;
    int t = threadIdx.x;
    float e = 0.f;
    #pragma unroll
    for (int c = 0; c < 4; ++c) e += partial[c * MROWS + b * TDIM + t];

    __shared__ float sm[512];
    sm[t] = e;
    __syncthreads();
    #pragma unroll
    for (int s = 256; s > 0; s >>= 1) {
        if (t < s) sm[t] = fmaxf(sm[t], sm[t + s]);
        __syncthreads();
    }
    float m = sm[0];
    __syncthreads();
    float ex = __expf(e - m);
    sm[t] = ex;
    __syncthreads();
    #pragma unroll
    for (int s = 256; s > 0; s >>= 1) {
        if (t < s) sm[t] += sm[t + s];
        __syncthreads();
    }
    float inv = 1.f / sm[0];
    wout[b * TDIM + t] = ex * inv;
}

__global__ __launch_bounds__(256) void k4_direct(const float* __restrict__ feats,
                                                 const float* __restrict__ weights,
                                                 float* __restrict__ out) {
    int b = blockIdx.y;
    int f4 = (blockIdx.x * 256 + threadIdx.x) * 4;
    __shared__ float wsm[TDIM];
    wsm[threadIdx.x]       = weights[b * TDIM + threadIdx.x];
    wsm[threadIdx.x + 256] = weights[b * TDIM + 256 + threadIdx.x];
    __syncthreads();

    const float* fp = feats + (size_t)b * TDIM * FEAT + f4;
    float ax = 0.f, ay = 0.f, az = 0.f, aw = 0.f;
    for (int t = 0; t < TDIM; ++t) {
        float4 v = *(const float4*)(fp + (size_t)t * FEAT);
        float w = wsm[t];
        ax += v.x * w; ay += v.y * w; az += v.z * w; aw += v.w * w;
    }
    float4 o = {ax, ay, az, aw};
    *(float4*)(out + (size_t)b * FEAT + f4) = o;
}

// ---------------------------------------------------------------------------
// Launch. d_out: [0, B*FEAT) attn_feats, [B*FEAT, +B*T) weights.
// d_out staging: Whb in weights region (dead after k2n); energies in attn
// region (dead after k3n). d_ws: bf16 U (2 MB) + pooling partials (8 MB).
// Branch on host-constant ws_size (graph-safe).
// ---------------------------------------------------------------------------
extern "C" void kernel_launch(void* const* d_in, const int* in_sizes, int n_in,
                              void* d_out, int out_size, void* d_ws, size_t ws_size,
                              hipStream_t stream) {
    const float* hidden = (const float*)d_in[0];
    const float* feats  = (const float*)d_in[1];
    const float* W      = (const float*)d_in[2];
    const float* U      = (const float*)d_in[3];
    const float* bias   = (const float*)d_in[4];
    const float* wvec   = (const float*)d_in[5];

    float* out         = (float*)d_out;
    float* attn_out    = out;
    float* weights_out = out + (size_t)BATCH * FEAT;
    float* whb         = weights_out;  // staged (dead after k2n)
    float* energies    = attn_out;     // staged (dead after k3n)

    const size_t uN        = (size_t)KDIM * FEAT;
    const size_t uBytes    = uN * sizeof(unsigned short);
    const size_t poolBytes = (size_t)TCH * BATCH * FEAT * sizeof(float);
    const bool fast = ws_size >= uBytes + poolBytes;

    if (fast) {
        unsigned short* uBf = (unsigned short*)d_ws;
        float* pool4 = (float*)((char*)d_ws + uBytes);
        k0n<<<dim3(256 + 8192), 256, 0, stream>>>(U, hidden, W, bias, uBf, whb);
        k2n<<<dim3(MROWS / 128), 512, 0, stream>>>(feats, uBf, whb, wvec, energies);
        k3n<<<dim3(BATCH), 512, 0, stream>>>(energies, weights_out);
        k4n<<<dim3(TCH, BATCH), 256, 0, stream>>>(feats, weights_out, pool4);
        k5_reduce<<<dim3(BATCH * FEAT / 4 / 256), 256, 0, stream>>>(pool4, attn_out);
    } else {
        k1_whb<<<dim3(KDIM / 4, BATCH), 256, 0, stream>>>(hidden, W, bias, whb);
        k2_energy<<<dim3(MROWS / 128, KDIM / 128), 256, 0, stream>>>(
            feats, U, whb, wvec, energies);
        k3_softmax<<<dim3(BATCH), 512, 0, stream>>>(energies, weights_out);
        k4_direct<<<dim3(FEAT / 1024, BATCH), 256, 0, stream>>>(
            feats, weights_out, attn_out);
    }
}